// Round 10
// baseline (101.230 us; speedup 1.0000x reference)
//
#include <hip/hip_runtime.h>
#include <hip/hip_bf16.h>

// Problem: B=4, LQ=LK=1024, NHEADS=16, DK=64, D_MODEL=1024.
// out[b,i,d] = 0.125 * sum_{n,k} q[b,i,n,k] * T[b,n,k,d] + fc_b[d]
// T[b,n,k,d] = sum_j k[b,j,n,k] * fc_w[d, j*16+n]
// stage1 (gemm1f): T2t[b][d][n*64+kk] = sum_j fc_w[d][j*16+n] * Kt[n][b*64+kk][j]
//   block = 16-d tile x ALL 16 heads x one batch -> full fc_w line consumption.
//   B double-buffered (stage t+1 under compute t), A single-buffer LDS with
//   derived conflict-free layout. Counted vmcnt throughout.
// stage2 (gemm2): out[b] = 0.125 * Qb[b] @ T2t[b]^T + bias.
// q->bf16 conversion rides gemm1f's epilogue.

typedef unsigned short u16;
typedef unsigned int u32;
typedef __bf16 bf16x8 __attribute__((ext_vector_type(8)));
typedef float f32x4 __attribute__((ext_vector_type(4)));

#define AS1 __attribute__((address_space(1)))
#define AS3 __attribute__((address_space(3)))

__device__ __forceinline__ u16 f2bf(float f) {
  union { float f; unsigned u; } in;
  in.f = f;
  unsigned u = in.u;
  u += 0x7fffu + ((u >> 16) & 1u);  // RNE
  return (u16)(u >> 16);
}

__device__ __forceinline__ u32 cvt_pk_bf16(float lo, float hi) {
  u32 r;
  asm("v_cvt_pk_bf16_f32 %0, %1, %2" : "=v"(r) : "v"(lo), "v"(hi));
  return r;
}

// ---------------- prep_k: Kt[n][b*64+kk][j] = k[b][j][n][kk] (proven) ----------------
__global__ __launch_bounds__(256) void prep_k(const float* __restrict__ k,
                                              u16* __restrict__ Kt) {
  __shared__ u16 lds[64][65];
  const int tid = threadIdx.x;
  const int bid = blockIdx.x;
  int jt = bid & 15, n = (bid >> 4) & 15, b = bid >> 8;
  const int j0 = jt * 64;
  float4 r[4];
#pragma unroll
  for (int it = 0; it < 4; ++it) {
    int idx = it * 256 + tid;
    int jj = idx >> 4;
    int c4 = idx & 15;
    r[it] = *reinterpret_cast<const float4*>(
        &k[(((size_t)b * 1024 + j0 + jj) * 16 + n) * 64 + c4 * 4]);
  }
#pragma unroll
  for (int it = 0; it < 4; ++it) {
    int idx = it * 256 + tid;
    int jj = idx >> 4;
    int c4 = idx & 15;
    lds[c4 * 4 + 0][jj] = f2bf(r[it].x);
    lds[c4 * 4 + 1][jj] = f2bf(r[it].y);
    lds[c4 * 4 + 2][jj] = f2bf(r[it].z);
    lds[c4 * 4 + 3][jj] = f2bf(r[it].w);
  }
  __syncthreads();
  ushort4 o[4];
#pragma unroll
  for (int it = 0; it < 4; ++it) {
    int idx = it * 256 + tid;
    int kk = idx >> 4;
    int c4 = idx & 15;
    o[it].x = lds[kk][c4 * 4 + 0]; o[it].y = lds[kk][c4 * 4 + 1];
    o[it].z = lds[kk][c4 * 4 + 2]; o[it].w = lds[kk][c4 * 4 + 3];
  }
#pragma unroll
  for (int it = 0; it < 4; ++it) {
    int idx = it * 256 + tid;
    int kk = idx >> 4;
    int c4 = idx & 15;
    *reinterpret_cast<ushort4*>(
        &Kt[((size_t)n * 256 + b * 64 + kk) * 1024 + j0 + c4 * 4]) = o[it];
  }
}

// ---------------- gemm1f v3: B-dbuf pipelined fused de-interleave GEMM ----------------
// 256 blocks: o -> wg=(o&7)*32+(o>>3) (XCD-bijective; 4 batch-siblings of a
// d-slab share one XCD's L2); tm=wg>>2 (16-d tile), b=wg&3.
// A layout (u32): addr = n*260 + dd*16 + (jp ^ ((dd&3)<<2))
//   write: 2-way bank alias (free). read af (bf16x8 @ u16 n*520+lr*32+(lg^(lr&3))*8):
//   linear 16B-block tiling -> conflict-free.
// B layout: [1024 rows][32 j] per buffer, chunk-swizzle c^=(row&3)^((row>>2)&3)
//   applied on BOTH gl_lds source and ds_read (rule #21).
__global__ __launch_bounds__(256, 1) void gemm1f(const float* __restrict__ fw,
                                                 const u16* __restrict__ Kt,
                                                 u16* __restrict__ T2t,
                                                 const float* __restrict__ qsrc,
                                                 u16* __restrict__ qdst) {
  __shared__ __align__(16) u16 Bbuf[2][1024 * 32];  // 128 KB
  __shared__ __align__(16) u32 Albuf[16 * 260];     // 16.25 KB
  const int tid = threadIdx.x;
  const int w = tid >> 6, lane = tid & 63;
  const int o = blockIdx.x;
  const int wg = (o & 7) * 32 + (o >> 3);
  const int tm = wg >> 2, b = wg & 3;
  const int d0 = tm * 16;
  const int lr = lane & 15, lg = lane >> 4;

  f32x4 acc[4][4] = {};  // [head-within-wave hh][kk-frag ni]
  float4 rA[8];          // prefetched A pairs: rA[2i]=j even, rA[2i+1]=j odd

  auto issueA = [&](int t) {
    const int kt = t * 32;
#pragma unroll
    for (int i = 0; i < 4; ++i) {
      int p = i * 256 + tid;
      int nq = p & 3, jp = (p >> 2) & 15, dd = p >> 6;
      const float* base = fw + (size_t)(d0 + dd) * 16384 + (size_t)(kt + 2 * jp) * 16 + nq * 4;
      rA[2 * i]     = *reinterpret_cast<const float4*>(base);
      rA[2 * i + 1] = *reinterpret_cast<const float4*>(base + 16);
    }
  };
  auto writeA = [&]() {
#pragma unroll
    for (int i = 0; i < 4; ++i) {
      int p = i * 256 + tid;
      int nq = p & 3, jp = (p >> 2) & 15, dd = p >> 6;
      int base = dd * 16 + (jp ^ ((dd & 3) << 2));
#pragma unroll
      for (int e = 0; e < 4; ++e)
        Albuf[(4 * nq + e) * 260 + base] =
            cvt_pk_bf16((&rA[2 * i].x)[e], (&rA[2 * i + 1].x)[e]);
    }
  };
  auto stageB = [&](int t, int buf) {
    const int kt = t * 32;
    u16* dstb = &Bbuf[buf][0];
#pragma unroll
    for (int i = 0; i < 16; ++i) {
      int p = i * 256 + tid;          // 0..4095 16B chunks
      int row = p >> 2, c = p & 3;    // row = n*64+kk
      int n = row >> 6, kk = row & 63;
      int sc = c ^ (row & 3) ^ ((row >> 2) & 3);
      const u16* src = Kt + ((size_t)n * 256 + b * 64 + kk) * 1024 + kt + sc * 8;
      __builtin_amdgcn_global_load_lds((const AS1 void*)src,
                                       (AS3 void*)(dstb + p * 8), 16, 0, 0);
    }
  };
  auto compute = [&](int buf) {
    const u16* AB16 = reinterpret_cast<const u16*>(&Albuf[0]);
    const u16* BB = &Bbuf[buf][0];
#pragma unroll
    for (int hh = 0; hh < 4; ++hh) {
      const int n = w * 4 + hh;
      bf16x8 af = *reinterpret_cast<const bf16x8*>(
          &AB16[n * 520 + lr * 32 + (lg ^ (lr & 3)) * 8]);
#pragma unroll
      for (int ni = 0; ni < 4; ++ni) {
        int row = n * 64 + ni * 16 + lr;
        int cc = lg ^ (row & 3) ^ ((row >> 2) & 3);
        bf16x8 bq = *reinterpret_cast<const bf16x8*>(&BB[row * 32 + cc * 8]);
        acc[hh][ni] = __builtin_amdgcn_mfma_f32_16x16x32_bf16(af, bq, acc[hh][ni], 0, 0, 0);
      }
    }
  };

  // prologue: B(0) + A(0) in flight; A(0) -> LDS; A(1) in flight
  stageB(0, 0);
  issueA(0);
  asm volatile("s_waitcnt vmcnt(0)" ::: "memory");
  writeA();
  issueA(1);
  asm volatile("s_waitcnt lgkmcnt(0)" ::: "memory");
  __builtin_amdgcn_s_barrier();

  for (int t = 0; t < 32; ++t) {
    if (t < 31) stageB(t + 1, (t + 1) & 1);  // B(t+1) lands under compute(t)
    compute(t & 1);
    if (t < 31) {
      __builtin_amdgcn_s_barrier();                        // Albuf consumed
      asm volatile("s_waitcnt vmcnt(16)" ::: "memory");    // A(t+1) regs ready
      writeA();
      if (t < 30) {
        issueA(t + 2);
        asm volatile("s_waitcnt vmcnt(8)" ::: "memory");   // B(t+1) landed
      } else {
        asm volatile("s_waitcnt vmcnt(0)" ::: "memory");   // tail: B(31) landed
      }
      asm volatile("s_waitcnt lgkmcnt(0)" ::: "memory");
      __builtin_amdgcn_s_barrier();                        // A writes visible
    }
  }

  // epilogue: C frag col=lane&15, row=(lane>>4)*4+q -> T2t[b][d0+row][n*64+col]
#pragma unroll
  for (int hh = 0; hh < 4; ++hh) {
    const int n = w * 4 + hh;
#pragma unroll
    for (int ni = 0; ni < 4; ++ni) {
#pragma unroll
      for (int qq = 0; qq < 4; ++qq) {
        T2t[(size_t)b * 1048576 + (size_t)(d0 + lg * 4 + qq) * 1024 +
            n * 64 + ni * 16 + lr] = f2bf(acc[hh][ni][qq]);
      }
    }
  }

  // q-tail: stream-convert this block's 64KB chunk of q -> Qb
  const float4* src = reinterpret_cast<const float4*>(qsrc) + (size_t)o * 4096;
  ushort4* dst = reinterpret_cast<ushort4*>(qdst) + (size_t)o * 4096;
#pragma unroll
  for (int rnd = 0; rnd < 4; ++rnd) {
    float4 r[4];
#pragma unroll
    for (int i = 0; i < 4; ++i) r[i] = src[rnd * 1024 + i * 256 + tid];
#pragma unroll
    for (int i = 0; i < 4; ++i) {
      ushort4 oo;
      oo.x = f2bf(r[i].x); oo.y = f2bf(r[i].y);
      oo.z = f2bf(r[i].z); oo.w = f2bf(r[i].w);
      dst[rnd * 1024 + i * 256 + tid] = oo;
    }
  }
}

// ---------------- gemm2 (unchanged, proven): out = 0.125 * Qb @ T2t^T + bias ----------------
template <int VM>
__device__ __forceinline__ void waitVm() {
  if constexpr (VM == 16) asm volatile("s_waitcnt vmcnt(16)" ::: "memory");
  else if constexpr (VM == 8) asm volatile("s_waitcnt vmcnt(8)" ::: "memory");
  else asm volatile("s_waitcnt vmcnt(0)" ::: "memory");
}

__global__ __launch_bounds__(256, 1) void gemm2(const u16* __restrict__ Abase,
                                                const u16* __restrict__ Bbase,
                                                float* __restrict__ CoutF,
                                                const float* __restrict__ bias) {
  __shared__ u16 AB[4][2][128 * 64];  // 128 KB
  const int tid = threadIdx.x;
  const int wid = tid >> 6;
  const int lane = tid & 63;
  const int batch = blockIdx.y;
  const int tm = blockIdx.x >> 3;
  const int tn = blockIdx.x & 7;

  const u16* A = Abase + (size_t)batch * 1048576;
  const u16* B = Bbase + (size_t)batch * 1048576;
  const int row0A = tm * 128, row0B = tn * 128;

  const int wr = wid >> 1;
  const int wc = wid & 1;
  const int laneRow = lane & 15;
  const int hi8 = (lane >> 4) * 8;
  const int swz = (lane & 7) * 8;

  f32x4 acc[4][4] = {};

  auto stage = [&](int tIdx) {
    const int kt = tIdx * 64;
    u16* lA = &AB[tIdx & 3][0][0];
    u16* lB = &AB[tIdx & 3][1][0];
#pragma unroll
    for (int i = 0; i < 4; ++i) {
      int p = i * 256 + tid;
      int r = p >> 3;
      int sc = ((p & 7) ^ (r & 7)) * 8;
      const u16* gA = A + (size_t)(row0A + r) * 1024 + kt + sc;
      const u16* gB = B + (size_t)(row0B + r) * 1024 + kt + sc;
      __builtin_amdgcn_global_load_lds((const AS1 void*)gA,
                                       (AS3 void*)(lA + i * 2048 + wid * 512), 16, 0, 0);
      __builtin_amdgcn_global_load_lds((const AS1 void*)gB,
                                       (AS3 void*)(lB + i * 2048 + wid * 512), 16, 0, 0);
    }
  };

  auto compute = [&](int tIdx) {
    const u16* At = &AB[tIdx & 3][0][0];
    const u16* Bt = &AB[tIdx & 3][1][0];
    bf16x8 af[2][4], bq[2][4];
#pragma unroll
    for (int kh = 0; kh < 2; ++kh) {
      int cs = (kh * 32 + hi8) ^ swz;
#pragma unroll
      for (int mi = 0; mi < 4; ++mi)
        af[kh][mi] = *reinterpret_cast<const bf16x8*>(
            &At[(wr * 64 + mi * 16 + laneRow) * 64 + cs]);
#pragma unroll
      for (int ni = 0; ni < 4; ++ni)
        bq[kh][ni] = *reinterpret_cast<const bf16x8*>(
            &Bt[(wc * 64 + ni * 16 + laneRow) * 64 + cs]);
    }
#pragma unroll
    for (int kh = 0; kh < 2; ++kh)
#pragma unroll
      for (int mi = 0; mi < 4; ++mi)
#pragma unroll
        for (int ni = 0; ni < 4; ++ni)
          acc[mi][ni] = __builtin_amdgcn_mfma_f32_16x16x32_bf16(
              af[kh][mi], bq[kh][ni], acc[mi][ni], 0, 0, 0);
  };

  stage(0); stage(1); stage(2);
  for (int t = 0; t < 13; ++t) {
    waitVm<16>();
    __builtin_amdgcn_s_barrier();
    stage(t + 3);
    compute(t);
  }
  waitVm<16>(); __builtin_amdgcn_s_barrier(); compute(13);
  waitVm<8>();  __builtin_amdgcn_s_barrier(); compute(14);
  waitVm<0>();  __builtin_amdgcn_s_barrier(); compute(15);

#pragma unroll
  for (int mi = 0; mi < 4; ++mi) {
#pragma unroll
    for (int ni = 0; ni < 4; ++ni) {
      int colg = tn * 128 + wc * 64 + ni * 16 + laneRow;
#pragma unroll
      for (int qq = 0; qq < 4; ++qq) {
        int rowg = tm * 128 + wr * 64 + mi * 16 + (lane >> 4) * 4 + qq;
        CoutF[(size_t)batch * 1048576 + (size_t)rowg * 1024 + colg] =
            acc[mi][ni][qq] * 0.125f + bias[colg];
      }
    }
  }
}

extern "C" void kernel_launch(void* const* d_in, const int* in_sizes, int n_in,
                              void* d_out, int out_size, void* d_ws, size_t ws_size,
                              hipStream_t stream) {
  const float* q    = (const float*)d_in[0];
  const float* k    = (const float*)d_in[1];
  // d_in[2] = v — unused by the reference output
  const float* fc_w = (const float*)d_in[3];
  const float* fc_b = (const float*)d_in[4];
  float* out = (float*)d_out;

  char* ws = (char*)d_ws;
  if (ws_size < 58720256) return;
  u16* Qb  = (u16*)(ws);             // [4][1024][1024]  8.4 MB
  u16* Kt  = (u16*)(ws + 8388608);   // [16][256][1024]  8.4 MB
  u16* T2t = (u16*)(ws + 50331648);  // [4][1024][1024]  8.4 MB

  prep_k<<<1024, 256, 0, stream>>>(k, Kt);
  gemm1f<<<256, 256, 0, stream>>>(fc_w, Kt, T2t, q, Qb);
  gemm2<<<dim3(64, 4), 256, 0, stream>>>(Qb, T2t, out, fc_b);
}